// Round 1
// baseline (520.972 us; speedup 1.0000x reference)
//
#include <hip/hip_runtime.h>

typedef __bf16 bf16x8 __attribute__((ext_vector_type(8)));
typedef float  f32x4  __attribute__((ext_vector_type(4)));

#define NTOK 256
#define DIM  128
#define NH   4

// LDS byte layout (72 KiB total):
//  QS  [256][32] bf16 swizzled        : 16384
//  KS  [256][32] bf16 swizzled        : 16384
//  VT  [32][256] bf16 swizzled (V^T)  : 16384
//  RG  union region (24576):
//     QKV phase : Wt [96][128] bf16 swizzled (qkv_w^T head slice)
//     attn phase: Pbuf 8 waves x 2 x 1 KiB  (16384)  +  PWt [128][32] bf16 (8192)
#define QS_OFF 0
#define KS_OFF 16384
#define VT_OFF 32768
#define RG_OFF 49152
#define PB_OFF 49152
#define PW_OFF 65536
#define SMEM_BYTES 73728

// [R][32] bf16 rows (64 B): XOR 16B-slot with (r>>1)&3 -> 8-row bank period, 2-way (free)
__device__ __forceinline__ int adr_r32(int r, int ib) { return (r << 6) + (ib ^ (((r >> 1) & 3) << 4)); }
// V^T [32][256] bf16 rows (512 B): XOR slot with n&7
__device__ __forceinline__ int adr_vt (int n, int ib) { return (n << 9) + (ib ^ ((n & 7) << 4)); }
// Wt [96][128] bf16 rows (256 B): XOR slot with c&7
__device__ __forceinline__ int adr_wt (int c, int ib) { return (c << 8) + (ib ^ ((c & 7) << 4)); }

// Precompute relative-position bias directly in MFMA C-fragment layout:
// biasFrag[((h*16+rt)*16+ct)*64 + lane][j] = bias[h][rt*16 + (lane>>4)*4 + j][ct*16 + (lane&15)]
__global__ void bias_precompute(const float* __restrict__ bias_table,
                                float* __restrict__ bias_frag)
{
    const int g    = blockIdx.x * 256 + threadIdx.x;   // 0..65535
    const int lane = g & 63;
    const int tile = g >> 6;                           // ((h*16+rt)*16+ct)
    const int ct = tile & 15, rt = (tile >> 4) & 15, h = tile >> 8;
    const int lr = lane & 15, rg = lane >> 4;
    // rel idx = (ri-rj+15)*31 + (ci-cj+15); ri=rt, ci=rg*4+j, rj=ct, cj=lr
    const int base = (rt - ct + 15) * 31 + (rg * 4 - lr + 15);
    float4 v;
    v.x = bias_table[(base + 0) * 4 + h];
    v.y = bias_table[(base + 1) * 4 + h];
    v.z = bias_table[(base + 2) * 4 + h];
    v.w = bias_table[(base + 3) * 4 + h];
    *reinterpret_cast<float4*>(bias_frag + (size_t)g * 4) = v;
}

__global__ __launch_bounds__(512, 2) void fused_win_attn(
    const float* __restrict__ x, const float* __restrict__ noise,
    const float* __restrict__ qkv_w, const float* __restrict__ proj_w,
    const float* __restrict__ proj_b, const float* __restrict__ bias_table,
    const float* __restrict__ noise_strength, const float* __restrict__ bias_frag,
    float* __restrict__ out)
{
    extern __shared__ char smem[];
    const int b    = blockIdx.x;
    const int tid  = threadIdx.x;
    const int wave = tid >> 6;
    const int lane = tid & 63;
    const int lr   = lane & 15;   // A-frag row / C-frag col
    const int hi   = lane >> 4;   // A-frag k-chunk / C-frag row-group
    const int wrow = wave * 32;   // this wave owns token rows [wrow, wrow+32)

    const float ns    = noise_strength[0];
    const float scale = 0.17677669529663689f;  // 32^-0.5, folded into Q

    // ---- X A-fragments in registers (noise added, bf16), reused by all heads ----
    bf16x8 Xf[2][4];
#pragma unroll
    for (int rb = 0; rb < 2; ++rb) {
        const int row = wrow + rb * 16 + lr;
        const float nz = noise[(size_t)b * NTOK + row] * ns;
        const float* prow = x + ((size_t)b * NTOK + row) * DIM;
#pragma unroll
        for (int kc = 0; kc < 4; ++kc) {
            float4 a0 = *reinterpret_cast<const float4*>(prow + kc * 32 + hi * 8);
            float4 a1 = *reinterpret_cast<const float4*>(prow + kc * 32 + hi * 8 + 4);
            bf16x8 v;
            v[0] = (__bf16)(a0.x + nz); v[1] = (__bf16)(a0.y + nz);
            v[2] = (__bf16)(a0.z + nz); v[3] = (__bf16)(a0.w + nz);
            v[4] = (__bf16)(a1.x + nz); v[5] = (__bf16)(a1.y + nz);
            v[6] = (__bf16)(a1.z + nz); v[7] = (__bf16)(a1.w + nz);
            Xf[rb][kc] = v;
        }
    }

    // ---- fused output accumulator: out rows [wrow,wrow+32) x 128 cols, f32 ----
    f32x4 acc[2][8];
#pragma unroll
    for (int rb = 0; rb < 2; ++rb)
#pragma unroll
        for (int ct = 0; ct < 8; ++ct)
            acc[rb][ct] = (f32x4){0.f, 0.f, 0.f, 0.f};

    for (int h = 0; h < NH; ++h) {
        __syncthreads();  // protect RG/QS/KS/VT overwrite vs previous head's readers
        // ---- stage qkv_w^T head slice: Wt[colLocal 0..95][k 0..127] bf16 ----
        for (int e = tid; e < 96 * 128; e += 512) {
            const int k = e / 96;
            const int i = e - k * 96;
            const int colg = (i < 32) ? (h * 32 + i)
                           : (i < 64) ? (128 + h * 32 + (i - 32))
                                      : (256 + h * 32 + (i - 64));
            *reinterpret_cast<__bf16*>(smem + RG_OFF + adr_wt(i, k * 2)) =
                (__bf16)qkv_w[k * 384 + colg];
        }
        __syncthreads();

        // ---- QKV GEMM: this wave's 32 rows x 96 cols, K=128 ----
#pragma unroll
        for (int rb = 0; rb < 2; ++rb) {
#pragma unroll
            for (int ct = 0; ct < 6; ++ct) {
                f32x4 c = (f32x4){0.f, 0.f, 0.f, 0.f};
#pragma unroll
                for (int kc = 0; kc < 4; ++kc) {
                    const bf16x8 wfrag = *reinterpret_cast<const bf16x8*>(
                        smem + RG_OFF + adr_wt(ct * 16 + lr, kc * 64 + hi * 16));
                    c = __builtin_amdgcn_mfma_f32_16x16x32_bf16(Xf[rb][kc], wfrag, c, 0, 0, 0);
                }
                // C layout: row=(hi*4+j), col=lr  -> scatter to Q/K/V^T LDS
#pragma unroll
                for (int j = 0; j < 4; ++j) {
                    const int t = wrow + rb * 16 + hi * 4 + j;
                    if (ct < 2) {
                        *reinterpret_cast<__bf16*>(smem + QS_OFF + adr_r32(t, (ct * 16 + lr) * 2)) =
                            (__bf16)(c[j] * scale);
                    } else if (ct < 4) {
                        *reinterpret_cast<__bf16*>(smem + KS_OFF + adr_r32(t, ((ct - 2) * 16 + lr) * 2)) =
                            (__bf16)c[j];
                    } else {
                        *reinterpret_cast<__bf16*>(smem + VT_OFF + adr_vt((ct - 4) * 16 + lr, t * 2)) =
                            (__bf16)c[j];
                    }
                }
            }
        }
        __syncthreads();
        // ---- stage proj_w^T head slice: PWt[n 0..127][kk 0..31] (Wt region now dead) ----
        for (int e = tid; e < 128 * 32; e += 512) {
            const int kk = e >> 7;
            const int n  = e & 127;
            *reinterpret_cast<__bf16*>(smem + PW_OFF + adr_r32(n, kk * 2)) =
                (__bf16)proj_w[(h * 32 + kk) * 128 + n];
        }
        __syncthreads();

        // ---- attention + fused proj, per 16-row block ----
#pragma unroll 1
        for (int rb = 0; rb < 2; ++rb) {
            const int rt = wave * 2 + rb;  // global 16-row tile index
            const bf16x8 qf = *reinterpret_cast<const bf16x8*>(
                smem + QS_OFF + adr_r32(wrow + rb * 16 + lr, hi * 16));
            f32x4 S[16];
#pragma unroll
            for (int ct = 0; ct < 16; ++ct) {
                const bf16x8 kf = *reinterpret_cast<const bf16x8*>(
                    smem + KS_OFF + adr_r32(ct * 16 + lr, hi * 16));
                S[ct] = __builtin_amdgcn_mfma_f32_16x16x32_bf16(
                    qf, kf, (f32x4){0.f, 0.f, 0.f, 0.f}, 0, 0, 0);
            }
            // relative-position bias (S fragment layout)
            if (bias_frag) {
#pragma unroll
                for (int ct = 0; ct < 16; ++ct) {
                    const float4 bv = *reinterpret_cast<const float4*>(
                        bias_frag + ((((h * 16 + rt) * 16 + ct) * 64 + lane) << 2));
                    S[ct][0] += bv.x; S[ct][1] += bv.y; S[ct][2] += bv.z; S[ct][3] += bv.w;
                }
            } else {
#pragma unroll
                for (int ct = 0; ct < 16; ++ct) {
                    const int base = (rt - ct + 15) * 31 + (hi * 4 - lr + 15);
#pragma unroll
                    for (int j = 0; j < 4; ++j)
                        S[ct][j] += bias_table[(base + j) * 4 + h];
                }
            }
            // ---- softmax over the 256 cols (16 tiles in-reg + 16-lane shuffle reduce) ----
            f32x4 m = S[0];
#pragma unroll
            for (int ct = 1; ct < 16; ++ct)
#pragma unroll
                for (int j = 0; j < 4; ++j) m[j] = fmaxf(m[j], S[ct][j]);
#pragma unroll
            for (int msk = 1; msk < 16; msk <<= 1)
#pragma unroll
                for (int j = 0; j < 4; ++j) m[j] = fmaxf(m[j], __shfl_xor(m[j], msk, 64));

            f32x4 lsum = (f32x4){0.f, 0.f, 0.f, 0.f};
#pragma unroll
            for (int ct = 0; ct < 16; ++ct)
#pragma unroll
                for (int j = 0; j < 4; ++j) {
                    const float p = __expf(S[ct][j] - m[j]);
                    S[ct][j] = p;
                    lsum[j] += p;
                }
#pragma unroll
            for (int msk = 1; msk < 16; msk <<= 1)
#pragma unroll
                for (int j = 0; j < 4; ++j) lsum[j] += __shfl_xor(lsum[j], msk, 64);
            f32x4 rl;
#pragma unroll
            for (int j = 0; j < 4; ++j) rl[j] = 1.0f / lsum[j];

            // ---- PV: O(16x32) = P(16x256) @ V(256x32), P via per-wave LDS double buffer ----
            f32x4 O0 = (f32x4){0.f, 0.f, 0.f, 0.f};
            f32x4 O1 = (f32x4){0.f, 0.f, 0.f, 0.f};
            char* pb = smem + PB_OFF + wave * 2048;
#pragma unroll
            for (int kcc = 0; kcc < 8; ++kcc) {
                char* pbc = pb + ((kcc & 1) << 10);
#pragma unroll
                for (int tt = 0; tt < 2; ++tt)
#pragma unroll
                    for (int j = 0; j < 4; ++j)
                        *reinterpret_cast<__bf16*>(pbc + adr_r32(hi * 4 + j, (tt * 16 + lr) * 2)) =
                            (__bf16)S[kcc * 2 + tt][j];
                const bf16x8 pf = *reinterpret_cast<const bf16x8*>(pbc + adr_r32(lr, hi * 16));
                const bf16x8 v0 = *reinterpret_cast<const bf16x8*>(
                    smem + VT_OFF + adr_vt(lr, kcc * 64 + hi * 16));
                const bf16x8 v1 = *reinterpret_cast<const bf16x8*>(
                    smem + VT_OFF + adr_vt(16 + lr, kcc * 64 + hi * 16));
                O0 = __builtin_amdgcn_mfma_f32_16x16x32_bf16(pf, v0, O0, 0, 0, 0);
                O1 = __builtin_amdgcn_mfma_f32_16x16x32_bf16(pf, v1, O1, 0, 0, 0);
            }
            // normalize rows, round to bf16, fuse proj slice: acc += O @ proj_w[h*32:(h+1)*32, :]
#pragma unroll
            for (int j = 0; j < 4; ++j) {
                O0[j] *= rl[j];
                O1[j] *= rl[j];
                *reinterpret_cast<__bf16*>(pb + adr_r32(hi * 4 + j, lr * 2))        = (__bf16)O0[j];
                *reinterpret_cast<__bf16*>(pb + adr_r32(hi * 4 + j, (16 + lr) * 2)) = (__bf16)O1[j];
            }
            const bf16x8 of = *reinterpret_cast<const bf16x8*>(pb + adr_r32(lr, hi * 16));
#pragma unroll
            for (int ct = 0; ct < 8; ++ct) {
                const bf16x8 wf = *reinterpret_cast<const bf16x8*>(
                    smem + PW_OFF + adr_r32(ct * 16 + lr, hi * 16));
                acc[rb][ct] = __builtin_amdgcn_mfma_f32_16x16x32_bf16(of, wf, acc[rb][ct], 0, 0, 0);
            }
        }
    }

    // ---- epilogue: + proj_b, store f32 ----
#pragma unroll
    for (int rb = 0; rb < 2; ++rb)
#pragma unroll
        for (int ct = 0; ct < 8; ++ct) {
            const float pbv = proj_b[ct * 16 + lr];
#pragma unroll
            for (int j = 0; j < 4; ++j) {
                const int row = wrow + rb * 16 + hi * 4 + j;
                out[((size_t)b * NTOK + row) * DIM + ct * 16 + lr] = acc[rb][ct][j] + pbv;
            }
        }
}

extern "C" void kernel_launch(void* const* d_in, const int* in_sizes, int n_in,
                              void* d_out, int out_size, void* d_ws, size_t ws_size,
                              hipStream_t stream)
{
    const float* x          = (const float*)d_in[0];
    const float* noise      = (const float*)d_in[1];
    const float* qkv_w      = (const float*)d_in[2];
    const float* proj_w     = (const float*)d_in[3];
    const float* proj_b     = (const float*)d_in[4];
    const float* bias_table = (const float*)d_in[5];
    const float* nstr       = (const float*)d_in[6];
    float* out = (float*)d_out;

    (void)in_sizes; (void)n_in; (void)out_size;

    hipFuncSetAttribute(reinterpret_cast<const void*>(fused_win_attn),
                        hipFuncAttributeMaxDynamicSharedMemorySize, SMEM_BYTES);

    const float* bias_frag = nullptr;
    if (ws_size >= (size_t)(1 << 20)) {  // 1 MiB bias fragment table
        bias_precompute<<<256, 256, 0, stream>>>(bias_table, (float*)d_ws);
        bias_frag = (const float*)d_ws;
    }
    fused_win_attn<<<1024, 512, SMEM_BYTES, stream>>>(
        x, noise, qkv_w, proj_w, proj_b, bias_table, nstr, bias_frag, out);
}